// Round 2
// baseline (3079.960 us; speedup 1.0000x reference)
//
#include <hip/hip_runtime.h>
#include <hip/hip_bf16.h>

typedef __hip_bfloat16 bf16;

#define BN_EPS 1e-5f

// ---- dtype-adaptive load/store: FP32=true -> float*, false -> bf16* ----
template<bool FP32>
__device__ __forceinline__ float ld(const void* p, long i) {
    if constexpr (FP32) return ((const float*)p)[i];
    else                return (float)((const bf16*)p)[i];
}
template<bool FP32>
__device__ __forceinline__ void st(void* p, long i, float v) {
    if constexpr (FP32) ((float*)p)[i] = v;
    else                ((bf16*)p)[i] = (bf16)v;
}

// ---------------- dtype probe ----------------
// Reads first 4096 half-words of y as bf16 exponent fields.
// Genuine bf16 N(0,1): max exponent field ~129. fp32 read as bf16:
// low half-words have uniform bits -> exponent >= 141 essentially surely.
__global__ void dtype_probe_kernel(const unsigned short* __restrict__ y, int* __restrict__ flag)
{
    int tid = threadIdx.x;  // 64 threads
    int mx = 0;
    for (int i = tid; i < 4096; i += 64) {
        int e = (y[i] >> 7) & 0xFF;
        mx = max(mx, e);
    }
    #pragma unroll
    for (int off = 32; off > 0; off >>= 1)
        mx = max(mx, __shfl_down(mx, off, 64));
    if (tid == 0) *flag = (mx >= 141) ? 1 : 0;
}

// ---------------- fused MLP: f -> memory_filters, g, h ----------------
// grid = 13 blocks (one per slot), 256 threads.
template<bool FP32>
__global__ __launch_bounds__(256) void mlp_kernel(
    const void* __restrict__ w1, const void* __restrict__ b1,
    const void* __restrict__ w2, const void* __restrict__ b2,
    const void* __restrict__ w3, const void* __restrict__ b3,
    const void* __restrict__ c2w, const void* __restrict__ c2b,
    void* __restrict__ d_out,          // memory_filters at offset 0
    float* __restrict__ g_out,         // 13*32
    float* __restrict__ h_out,         // 13
    const int* __restrict__ flag)
{
    if (*flag != (FP32 ? 1 : 0)) return;

    __shared__ float f1[1024];
    __shared__ float f2[2048];
    __shared__ float f3[96];
    __shared__ float fn[96];
    __shared__ float inv_s;

    int s   = blockIdx.x;
    int tid = threadIdx.x;

    // f1 = relu(w1[s,:] + b1)
    for (int j = tid; j < 1024; j += 256)
        f1[j] = fmaxf(ld<FP32>(w1, s * 1024 + j) + ld<FP32>(b1, j), 0.f);
    __syncthreads();

    // f2 = relu(f1 @ w2 + b2), 8 outputs per thread, j-outer for ILP
    {
        float acc[8];
        #pragma unroll
        for (int i = 0; i < 8; ++i) acc[i] = ld<FP32>(b2, tid + 256 * i);
        for (int j = 0; j < 1024; ++j) {
            float a = f1[j];
            long base = (long)j * 2048 + tid;
            #pragma unroll
            for (int i = 0; i < 8; ++i)
                acc[i] = fmaf(a, ld<FP32>(w2, base + 256 * i), acc[i]);
        }
        #pragma unroll
        for (int i = 0; i < 8; ++i) f2[tid + 256 * i] = fmaxf(acc[i], 0.f);
    }
    __syncthreads();

    // f3 = f2 @ w3 + b3 (96 outputs; 4 partial accumulators for ILP)
    if (tid < 96) {
        float a0 = 0.f, a1 = 0.f, a2 = 0.f, a3 = 0.f;
        for (int k = 0; k < 2048; k += 4) {
            a0 = fmaf(f2[k],     ld<FP32>(w3, (long)(k)     * 96 + tid), a0);
            a1 = fmaf(f2[k + 1], ld<FP32>(w3, (long)(k + 1) * 96 + tid), a1);
            a2 = fmaf(f2[k + 2], ld<FP32>(w3, (long)(k + 2) * 96 + tid), a2);
            a3 = fmaf(f2[k + 3], ld<FP32>(w3, (long)(k + 3) * 96 + tid), a3);
        }
        f3[tid] = ld<FP32>(b3, tid) + ((a0 + a1) + (a2 + a3));
    }
    __syncthreads();

    if (tid == 0) {
        float ss = 0.f;
        for (int c = 0; c < 96; ++c) ss += f3[c] * f3[c];
        inv_s = 1.f / fmaxf(sqrtf(ss), 1e-12f);
    }
    __syncthreads();

    if (tid < 96) {
        float v = f3[tid] * inv_s;
        fn[tid] = v;
        st<FP32>(d_out, s * 96 + tid, v);   // memory_filters
    }
    __syncthreads();

    // g[s,c] = sum_o fn[o] * conv2_w[o,c];  h[s] = sum_o fn[o] * conv2_b[o]
    if (tid < 32) {
        float g = 0.f;
        #pragma unroll
        for (int o = 0; o < 96; ++o) g = fmaf(fn[o], ld<FP32>(c2w, o * 32 + tid), g);
        g_out[s * 32 + tid] = g;
    } else if (tid == 64) {
        float hv = 0.f;
        for (int o = 0; o < 96; ++o) hv = fmaf(fn[o], ld<FP32>(c2b, o), hv);
        h_out[s] = hv;
    }
}

// ---------------- fused conv1 + BN + PReLU + (g,h) projection -> logits ----------------
// grid = 2*96*96 blocks (one per (b,h,w) row of 96 d), 256 threads.
// thread: oc = tid&31, 12 consecutive d at (tid>>5)*12.
template<bool FP32>
__global__ __launch_bounds__(256) void conv_fused_kernel(
    const void* __restrict__ y, const void* __restrict__ w1c, const void* __restrict__ b1c,
    const void* __restrict__ gamma, const void* __restrict__ beta,
    const void* __restrict__ mean,  const void* __restrict__ var,
    const void* __restrict__ alpha_p,
    const float* __restrict__ g_in, const float* __restrict__ h_in,
    void* __restrict__ d_out,
    const int* __restrict__ flag)
{
    if (*flag != (FP32 ? 1 : 0)) return;

    __shared__ float y_tile[72 * 98];   // 8 ic x 9 (dz,dy) x 98 d (zero halo)
    __shared__ float t_tile[32 * 97];   // [oc][d] +1 pad
    __shared__ float g_sh[13 * 32];
    __shared__ float h_sh[13];
    __shared__ float bninv[32], bnbias[32], cb[32];
    __shared__ float alpha_sh;

    int tid = threadIdx.x;
    int bid = blockIdx.x;
    int b   = bid / 9216;
    int rem = bid - b * 9216;
    int h   = rem / 96;
    int w   = rem - h * 96;

    for (int j = tid; j < 13 * 32; j += 256) g_sh[j] = g_in[j];
    if (tid < 13) h_sh[tid] = h_in[tid];
    if (tid >= 32 && tid < 64) {
        int c = tid - 32;
        float iv = ld<FP32>(gamma, c) * rsqrtf(ld<FP32>(var, c) + BN_EPS);
        bninv[c]  = iv;
        bnbias[c] = ld<FP32>(beta, c) - ld<FP32>(mean, c) * iv;
        cb[c]     = ld<FP32>(b1c, c);
    }
    if (tid == 64) alpha_sh = ld<FP32>(alpha_p, 0);

    int oc = tid & 31;
    int dg = tid >> 5;
    int D0 = dg * 12;

    float acc[12];
    #pragma unroll
    for (int i = 0; i < 12; ++i) acc[i] = 0.f;

    for (int ch = 0; ch < 4; ++ch) {
        __syncthreads();
        for (int j = tid; j < 72 * 98; j += 256) {
            int r    = j / 98;
            int pos  = j - r * 98;
            int icl  = r / 9;
            int dzdy = r - icl * 9;
            int dz = dzdy / 3;
            int dy = dzdy - dz * 3;
            int hh2 = h + dz - 1;
            int ww2 = w + dy - 1;
            int dd  = pos - 1;
            float v = 0.f;
            if ((unsigned)hh2 < 96u && (unsigned)ww2 < 96u && (unsigned)dd < 96u) {
                int ic = ch * 8 + icl;
                v = ld<FP32>(y, (((long)(b * 32 + ic) * 96 + hh2) * 96 + ww2) * 96 + dd);
            }
            y_tile[j] = v;
        }
        __syncthreads();
        for (int icl = 0; icl < 8; ++icl) {
            int ic = ch * 8 + icl;
            long wbase = (long)(oc * 32 + ic) * 27;
            float wr[27];
            #pragma unroll
            for (int t2 = 0; t2 < 27; ++t2) wr[t2] = ld<FP32>(w1c, wbase + t2);
            #pragma unroll
            for (int dzdy = 0; dzdy < 9; ++dzdy) {
                const float* row = &y_tile[(icl * 9 + dzdy) * 98 + D0];
                float r[14];
                #pragma unroll
                for (int q = 0; q < 14; ++q) r[q] = row[q];
                float w0 = wr[dzdy * 3], w1v = wr[dzdy * 3 + 1], w2v = wr[dzdy * 3 + 2];
                #pragma unroll
                for (int i = 0; i < 12; ++i) {
                    acc[i] = fmaf(w0,  r[i],     acc[i]);
                    acc[i] = fmaf(w1v, r[i + 1], acc[i]);
                    acc[i] = fmaf(w2v, r[i + 2], acc[i]);
                }
            }
        }
    }

    // BN + PReLU -> t_tile
    {
        float iv = bninv[oc], bb = bnbias[oc], cbv = cb[oc], al = alpha_sh;
        #pragma unroll
        for (int i = 0; i < 12; ++i) {
            float v = (acc[i] + cbv) * iv + bb;
            v = (v >= 0.f) ? v : al * v;
            t_tile[oc * 97 + D0 + i] = v;
        }
    }
    __syncthreads();

    // logits[b,s,h,w,:] = t . g[s] + h[s]   (single +1248 offset, relative to d_out)
    long obase = 1248 + (long)b * 13 * 884736 + (long)h * 9216 + (long)w * 96;
    for (int j = tid; j < 13 * 96; j += 256) {
        int s = j / 96;
        int d = j - s * 96;
        float a = h_sh[s];
        const float* gp = &g_sh[s * 32];
        #pragma unroll
        for (int o = 0; o < 32; ++o)
            a = fmaf(t_tile[o * 97 + d], gp[o], a);
        st<FP32>(d_out, obase + (long)s * 884736 + d, a);
    }
}

extern "C" void kernel_launch(void* const* d_in, const int* in_sizes, int n_in,
                              void* d_out, int out_size, void* d_ws, size_t ws_size,
                              hipStream_t stream) {
    const void* y       = d_in[0];
    const void* conv1_w = d_in[1];
    const void* conv1_b = d_in[2];
    const void* bn_g    = d_in[3];
    const void* bn_b    = d_in[4];
    const void* bn_m    = d_in[5];
    const void* bn_v    = d_in[6];
    const void* alpha   = d_in[7];
    const void* conv2_w = d_in[8];
    const void* conv2_b = d_in[9];
    const void* w1      = d_in[10];
    const void* b1      = d_in[11];
    const void* w2      = d_in[12];
    const void* b2      = d_in[13];
    const void* w3      = d_in[14];
    const void* b3      = d_in[15];

    // ws layout (floats): [0..15] flag + pad, [16..431] g (13*32), [432..444] h (13)
    int*   ws_flag = (int*)d_ws;
    float* ws_f    = (float*)d_ws;
    float* ws_g    = ws_f + 16;
    float* ws_h    = ws_f + 16 + 416;

    dtype_probe_kernel<<<1, 64, 0, stream>>>((const unsigned short*)y, ws_flag);

    mlp_kernel<false><<<13, 256, 0, stream>>>(w1, b1, w2, b2, w3, b3, conv2_w, conv2_b,
                                              d_out, ws_g, ws_h, ws_flag);
    mlp_kernel<true ><<<13, 256, 0, stream>>>(w1, b1, w2, b2, w3, b3, conv2_w, conv2_b,
                                              d_out, ws_g, ws_h, ws_flag);

    conv_fused_kernel<false><<<2 * 96 * 96, 256, 0, stream>>>(
        y, conv1_w, conv1_b, bn_g, bn_b, bn_m, bn_v, alpha, ws_g, ws_h, d_out, ws_flag);
    conv_fused_kernel<true ><<<2 * 96 * 96, 256, 0, stream>>>(
        y, conv1_w, conv1_b, bn_g, bn_b, bn_m, bn_v, alpha, ws_g, ws_h, d_out, ws_flag);
}